// Round 1
// 251.164 us; speedup vs baseline: 1.0327x; 1.0327x over previous
//
#include <hip/hip_runtime.h>
#include <hip/hip_bf16.h>

// B=4, S=2048, D=1024.  M = B*S = 8192.
// Workspace layout (bytes):
//   [0,         33554432)  : E bf16 (4*2048*2048) = exp(scores)
//     overlay (dead before qk runs):
//     [0,         16777216) : Xb  bf16 (8192*1024)
//     [16777216,  23068672) : Wt  bf16 (3072*1024)
//   [50331648,  50364416)  : rowsum fp32 (8192)   (zeroed by setup)
//   [67108864,  83886080)  : Q bf16 (8192*1024)
//   [83886080, 100663296)  : K bf16 (8192*1024)
//   [100663296,117440512)  : Vt bf16 (4*1024*2048) -- written DIRECTLY by qkv
//
// Pipeline (5 launches):
//   setup  : cast X->bf16, transpose W->Wt bf16, zero rowsum
//   qkv x2 : two 768-block dispatches (profiling visibility).
//   qk     : 1-wave blocks, 64x64 tiles, BK=32, E=exp(QK^T/32)+rowsums.
//   pv     : 1-wave core: out=(E x V)/rowsum.
//
// R8: qk/pv were latency-bound (MfmaUtil 13%, VALUBusy 10%, HBM 13%,
// occupancy 16% -- ALL pipes idle).  Old core: loads -> vmcnt(0) drain ->
// compute, serial per wave; each K-step paid full L2/L3 latency.  New
// gemm_core32p double-buffers LDS and uses COUNTED vmcnt (T3/T4): at iter
// it, wait vmcnt(8) (it+1's 8 loads stay in flight), ds_read buf, free it
// with lgkmcnt(0), immediately issue it+2's loads into it, then MFMA.
// 1-wave blocks have no s_barrier, so nothing forces a vmcnt(0) drain.
// sched_barrier(0) after each asm wait (rule #18) pins the schedule.
// LDS 8KB->16KB/block: still 10 blocks/CU >= 8.25 grid average.

typedef __attribute__((ext_vector_type(8))) short short8;
typedef __attribute__((ext_vector_type(4))) short s16x4;
typedef __attribute__((ext_vector_type(4))) float f32x4;

__device__ __forceinline__ short f2bf(float f) {
  __hip_bfloat16 h = __float2bfloat16(f);
  return *reinterpret_cast<short*>(&h);
}

__device__ __forceinline__ void gll16(const void* g, void* l) {
  __builtin_amdgcn_global_load_lds((const __attribute__((address_space(1))) void*)g,
                                   (__attribute__((address_space(3))) void*)l,
                                   16, 0, 0);
}

// ---------------------------------------------------------------------------
// 128x128-tile GEMM core, BK=64, 4 waves (qkv only).  XOR bank swizzle on
// 16B k-groups (R1->R2: LDS conflicts 6.3M -> 0).
// ---------------------------------------------------------------------------
__device__ __forceinline__ void gemm_core(const short* __restrict__ A,
                                          const short* __restrict__ Bt,
                                          int lda, int ldb,
                                          int row0, int col0, int kIters,
                                          f32x4 acc[4][4],
                                          short* lA, short* lB) {
  const int tid  = threadIdx.x;
  const int wave = tid >> 6;
  const int lane = tid & 63;
  const int quad = lane >> 4;
  const int l16  = lane & 15;

  const f32x4 zero = {0.f, 0.f, 0.f, 0.f};
#pragma unroll
  for (int i = 0; i < 4; ++i)
#pragma unroll
    for (int j = 0; j < 4; ++j) acc[i][j] = zero;

  const int srow = tid >> 3;                    // 0..31
  const int gcol = ((tid & 7) ^ (srow & 7)) * 8;
  const short* A1 = A + (size_t)(row0 + srow) * lda + gcol;
  const short* A2 = A + (size_t)(row0 + srow + 32) * lda + gcol;
  const short* A3 = A + (size_t)(row0 + srow + 64) * lda + gcol;
  const short* A4 = A + (size_t)(row0 + srow + 96) * lda + gcol;
  const short* B1 = Bt + (size_t)(col0 + srow) * ldb + gcol;
  const short* B2 = Bt + (size_t)(col0 + srow + 32) * ldb + gcol;
  const short* B3 = Bt + (size_t)(col0 + srow + 64) * ldb + gcol;
  const short* B4 = Bt + (size_t)(col0 + srow + 96) * ldb + gcol;

  short* lA1 = lA + wave * 512;
  short* lA2 = lA + 2048 + wave * 512;
  short* lA3 = lA + 4096 + wave * 512;
  short* lA4 = lA + 6144 + wave * 512;
  short* lB1 = lB + wave * 512;
  short* lB2 = lB + 2048 + wave * 512;
  short* lB3 = lB + 4096 + wave * 512;
  short* lB4 = lB + 6144 + wave * 512;

  const int rswz  = l16 & 7;
  const int slot0 = (quad ^ rswz) * 8;
  const int slot1 = ((4 + quad) ^ rswz) * 8;
  const short* aRow = lA + ((wave >> 1) * 64 + l16) * 64;
  const short* bRow = lB + ((wave & 1) * 64 + l16) * 64;

  for (int it = 0; it < kIters; ++it) {
    const int k0 = it * 64;
    gll16(A1 + k0, lA1);
    gll16(A2 + k0, lA2);
    gll16(A3 + k0, lA3);
    gll16(A4 + k0, lA4);
    gll16(B1 + k0, lB1);
    gll16(B2 + k0, lB2);
    gll16(B3 + k0, lB3);
    gll16(B4 + k0, lB4);
    __syncthreads();

#pragma unroll
    for (int s = 0; s < 2; ++s) {
      const int so = s ? slot1 : slot0;
      short8 af[4], bfr[4];
#pragma unroll
      for (int i = 0; i < 4; ++i) af[i] = *(const short8*)(aRow + i * 1024 + so);
#pragma unroll
      for (int j = 0; j < 4; ++j) bfr[j] = *(const short8*)(bRow + j * 1024 + so);
#pragma unroll
      for (int i = 0; i < 4; ++i)
#pragma unroll
        for (int j = 0; j < 4; ++j)
          acc[i][j] = __builtin_amdgcn_mfma_f32_16x16x32_bf16(af[i], bfr[j], acc[i][j], 0, 0, 0);
    }
    __syncthreads();
  }
}

// ---------------------------------------------------------------------------
// 64x64-tile GEMM core, BK=32, ONE wave, DOUBLE-BUFFERED + counted vmcnt.
// lA/lB are each 2 buffers of 2048 shorts (4KB): buf = (it&1)*2048.
// Same XOR swizzle as before: row r stores 16B k-group kg at slot
// kg ^ ((r>>1)&3) via the global source address; fragment reads undo it.
// Steady state per iter:
//   s_waitcnt vmcnt(8)        ; iter it's 8 loads done, it+1's in flight
//   8x ds_read_b128 (C++)     ; fragments from buf[it&1]
//   s_waitcnt lgkmcnt(0)      ; buffer free
//   8x global_load_lds        ; iter it+2 -> buf[it&1]  (issue-to-use = 2)
//   16x MFMA
// sched_barrier(0) after each asm wait pins ordering (rule #18).
// ---------------------------------------------------------------------------
__device__ __forceinline__ void gemm_core32p(const short* __restrict__ A,
                                             const short* __restrict__ Bt,
                                             int lda, int ldb,
                                             int row0, int col0, int kIters,
                                             f32x4 acc[4][4],
                                             short* lA, short* lB) {
  const int lane = threadIdx.x;      // 0..63
  const int quad = lane >> 4;
  const int l16  = lane & 15;

  const f32x4 zero = {0.f, 0.f, 0.f, 0.f};
#pragma unroll
  for (int i = 0; i < 4; ++i)
#pragma unroll
    for (int j = 0; j < 4; ++j) acc[i][j] = zero;

  // staging: set q (q=0..3) covers rows 16q..16q+15; lane l -> row 16q+(l>>2),
  // slot l&3; LDS dest = base + lane*16B.  ((row+16q)>>1)&3 is q-invariant.
  const int srow = lane >> 2;                        // 0..15
  const int gcol = ((lane & 3) ^ ((srow >> 1) & 3)) * 8;
  const short* A1 = A + (size_t)(row0 + srow) * lda + gcol;
  const short* A2 = A + (size_t)(row0 + srow + 16) * lda + gcol;
  const short* A3 = A + (size_t)(row0 + srow + 32) * lda + gcol;
  const short* A4 = A + (size_t)(row0 + srow + 48) * lda + gcol;
  const short* B1 = Bt + (size_t)(col0 + srow) * ldb + gcol;
  const short* B2 = Bt + (size_t)(col0 + srow + 16) * ldb + gcol;
  const short* B3 = Bt + (size_t)(col0 + srow + 32) * ldb + gcol;
  const short* B4 = Bt + (size_t)(col0 + srow + 48) * ldb + gcol;

  // fragment reads: row m = i*16+l16; ((m)>>1)&3 == (l16>>1)&3 for all i.
  const int slot = (quad ^ ((l16 >> 1) & 3)) * 8;

  // prologue: iter 0 -> buf0, iter 1 -> buf1
  {
    gll16(A1, lA);
    gll16(A2, lA + 512);
    gll16(A3, lA + 1024);
    gll16(A4, lA + 1536);
    gll16(B1, lB);
    gll16(B2, lB + 512);
    gll16(B3, lB + 1024);
    gll16(B4, lB + 1536);
  }
  if (kIters > 1) {
    short* a = lA + 2048;
    short* b = lB + 2048;
    gll16(A1 + 32, a);
    gll16(A2 + 32, a + 512);
    gll16(A3 + 32, a + 1024);
    gll16(A4 + 32, a + 1536);
    gll16(B1 + 32, b);
    gll16(B2 + 32, b + 512);
    gll16(B3 + 32, b + 1024);
    gll16(B4 + 32, b + 1536);
  }

  for (int it = 0; it < kIters; ++it) {
    const int bo = (it & 1) * 2048;
    if (it + 1 < kIters) {
      asm volatile("s_waitcnt vmcnt(8)" ::: "memory");
    } else {
      asm volatile("s_waitcnt vmcnt(0)" ::: "memory");
    }
    __builtin_amdgcn_sched_barrier(0);

    const short* aBase = lA + bo + l16 * 32 + slot;
    const short* bBase = lB + bo + l16 * 32 + slot;
    short8 af[4], bfr[4];
#pragma unroll
    for (int i = 0; i < 4; ++i) af[i] = *(const short8*)(aBase + i * 512);
#pragma unroll
    for (int j = 0; j < 4; ++j) bfr[j] = *(const short8*)(bBase + j * 512);

    asm volatile("s_waitcnt lgkmcnt(0)" ::: "memory");
    __builtin_amdgcn_sched_barrier(0);

    if (it + 2 < kIters) {
      const int k0 = (it + 2) * 32;
      short* a = lA + bo;
      short* b = lB + bo;
      gll16(A1 + k0, a);
      gll16(A2 + k0, a + 512);
      gll16(A3 + k0, a + 1024);
      gll16(A4 + k0, a + 1536);
      gll16(B1 + k0, b);
      gll16(B2 + k0, b + 512);
      gll16(B3 + k0, b + 1024);
      gll16(B4 + k0, b + 1536);
    }
    __builtin_amdgcn_sched_barrier(0);

#pragma unroll
    for (int i = 0; i < 4; ++i)
#pragma unroll
      for (int j = 0; j < 4; ++j)
        acc[i][j] = __builtin_amdgcn_mfma_f32_16x16x32_bf16(af[i], bfr[j], acc[i][j], 0, 0, 0);
  }
}

// C/D layout: row = quad*4 + reg, col = l16  (verified m89)
#define EPILOGUE_VARS                         \
  const int lane = threadIdx.x & 63;          \
  const int wave = threadIdx.x >> 6;          \
  const int quad = lane >> 4;                 \
  const int l16  = lane & 15;                 \
  const int rb   = (wave >> 1) * 64;          \
  const int cb   = (wave & 1) * 64;

// ---------------------------------------------------------------------------
// setup: blocks [0,8192) cast X->Xb; [8192,11264) transpose W->Wt;
//        [11264,11272) zero rowsum.
__global__ __launch_bounds__(256) void setup_kernel(const float* __restrict__ X,
                                                    const float* __restrict__ W,
                                                    short* __restrict__ Xb,
                                                    short* __restrict__ Wt,
                                                    float* __restrict__ rs) {
  const int bid = blockIdx.x;
  if (bid < 8192) {
    const int i = (bid * 256 + threadIdx.x) * 4;
    const f32x4 v = *(const f32x4*)(X + i);
    s16x4 o;
    o.x = f2bf(v.x); o.y = f2bf(v.y); o.z = f2bf(v.z); o.w = f2bf(v.w);
    *(s16x4*)(Xb + i) = o;
  } else if (bid < 11264) {
    __shared__ float tile[32][33];
    const int r  = bid - 8192;
    const int ni = r % 96;
    const int ki = r / 96;
    const int tx = threadIdx.x & 31;
    const int ty = threadIdx.x >> 5;
#pragma unroll
    for (int rr = 0; rr < 4; ++rr)
      tile[ty + rr * 8][tx] = W[(size_t)(ki * 32 + ty + rr * 8) * 3072 + ni * 32 + tx];
    __syncthreads();
#pragma unroll
    for (int rr = 0; rr < 4; ++rr)
      Wt[(size_t)(ni * 32 + ty + rr * 8) * 1024 + ki * 32 + tx] = f2bf(tile[tx][ty + rr * 8]);
  } else {
    const int i = (bid - 11264) * 1024 + threadIdx.x * 4;
    const f32x4 zero = {0.f, 0.f, 0.f, 0.f};
    *(f32x4*)(rs + i) = zero;
  }
}

// QKV: [8192x1024] x Wt[3072x1024]^T.  Q,K row-major [s][d]; V-columns
// written DIRECTLY transposed into Vt[b][d][s] via packed 8B stores.
__global__ __launch_bounds__(256) void qkv_gemm_kernel(const short* __restrict__ Xb,
                                                       const short* __restrict__ Wt,
                                                       short* __restrict__ Q,
                                                       short* __restrict__ K,
                                                       short* __restrict__ Vt,
                                                       int br0) {
  __shared__ short lA[8192], lB[8192];
  const int br = br0 + blockIdx.x / 24;
  const int bc = blockIdx.x % 24;
  f32x4 acc[4][4];
  gemm_core(Xb, Wt, 1024, 1024, br * 128, bc * 128, 16, acc, lA, lB);

  EPILOGUE_VARS
  const int rbase = br * 128 + rb;
  const int cbase = bc * 128 + cb;
  if (bc < 16) {
#pragma unroll
    for (int i = 0; i < 4; ++i)
#pragma unroll
      for (int j = 0; j < 4; ++j) {
        const int col = cbase + j * 16 + l16;
        short* dst = (col < 1024) ? Q : K;
        const int n = col & 1023;
#pragma unroll
        for (int r = 0; r < 4; ++r) {
          const int row = rbase + i * 16 + quad * 4 + r;
          dst[(size_t)row * 1024 + n] = f2bf(acc[i][j][r]);
        }
      }
  } else {
    const int b  = rbase >> 11;
    const int s0 = rbase & 2047;
    short* VtB = Vt + (size_t)b * 1024 * 2048;
#pragma unroll
    for (int i = 0; i < 4; ++i) {
      const int sb = s0 + i * 16 + quad * 4;
#pragma unroll
      for (int j = 0; j < 4; ++j) {
        const int d = cbase - 2048 + j * 16 + l16;
        s16x4 pk;
        pk.x = f2bf(acc[i][j][0]);
        pk.y = f2bf(acc[i][j][1]);
        pk.z = f2bf(acc[i][j][2]);
        pk.w = f2bf(acc[i][j][3]);
        *(s16x4*)(VtB + (size_t)d * 2048 + sb) = pk;
      }
    }
  }
}

// qk: 64x64 tiles, 1-wave blocks.  E = exp(QK^T/32) + rowsum atomics.
// Row-tile qi needs k-tiles 0..qi; diagonal tile (ki==qi) masks col>row.
// 528 tiles/batch x 4 = 2112 blocks, heavy rows first.
__global__ __launch_bounds__(64) void qk_kernel(const short* __restrict__ Q,
                                                const short* __restrict__ K,
                                                short* __restrict__ E,
                                                float* __restrict__ rs) {
  __shared__ short lA[4096], lB[4096];
  const int t = blockIdx.x >> 2;   // 0..527
  const int b = blockIdx.x & 3;
  int qi = 31, off = t;
  while (off >= qi + 1) { off -= qi + 1; qi--; }
  const int ki = off;

  f32x4 acc[4][4];
  const short* Qb = Q + (size_t)b * 2048 * 1024;
  const short* Kb = K + (size_t)b * 2048 * 1024;
  gemm_core32p(Qb, Kb, 1024, 1024, qi * 64, ki * 64, 32, acc, lA, lB);

  const int lane = threadIdx.x;
  const int quad = lane >> 4;
  const int l16  = lane & 15;
  short* Eb  = E + (size_t)b * 2048 * 2048;
  float* rsb = rs + b * 2048;
  const int rbase = qi * 64;
  const int cbase = ki * 64;
  const bool diag = (ki == qi);
#pragma unroll
  for (int i = 0; i < 4; ++i)
#pragma unroll
    for (int r = 0; r < 4; ++r) {
      const int row = rbase + i * 16 + quad * 4 + r;
      float partial = 0.f;
#pragma unroll
      for (int j = 0; j < 4; ++j) {
        const int col = cbase + j * 16 + l16;
        float e = __expf(acc[i][j][r] * 0.03125f);
        if (diag && col > row) e = 0.f;
        partial += e;
        Eb[(size_t)row * 2048 + col] = f2bf(e);
      }
      partial += __shfl_xor(partial, 1);
      partial += __shfl_xor(partial, 2);
      partial += __shfl_xor(partial, 4);
      partial += __shfl_xor(partial, 8);
      if (l16 == 0) atomicAdd(rsb + row, partial);
    }
}

// pv: 64x64 out tiles, 1-wave blocks.  out = (E x V)/rowsum.  K-extent per
// row-tile qi is (qi+1)*64 (causal).  32 qi x 16 dj x 4 b = 2048 blocks,
// heavy rows first.
__global__ __launch_bounds__(64) void pv_kernel(const short* __restrict__ E,
                                                const short* __restrict__ Vt,
                                                const float* __restrict__ rs,
                                                float* __restrict__ out) {
  __shared__ short lA[4096], lB[4096];
  const int t  = blockIdx.x >> 2;   // 0..511
  const int b  = blockIdx.x & 3;
  const int qi = 31 - (t >> 4);
  const int dj = t & 15;

  f32x4 acc[4][4];
  const short* Eb  = E + (size_t)b * 2048 * 2048;
  const short* Vtb = Vt + (size_t)b * 1024 * 2048;
  gemm_core32p(Eb, Vtb, 2048, 2048, qi * 64, dj * 64, (qi + 1) * 2, acc, lA, lB);

  const int lane = threadIdx.x;
  const int quad = lane >> 4;
  const int l16  = lane & 15;
  float* ob = out + (size_t)b * 2048 * 1024;
  const float* rsb = rs + b * 2048;
  const int rbase = qi * 64;
  const int cbase = dj * 64;
#pragma unroll
  for (int i = 0; i < 4; ++i)
#pragma unroll
    for (int r2 = 0; r2 < 4; ++r2) {
      const int row = rbase + i * 16 + quad * 4 + r2;
      const float inv = 1.f / rsb[row];
#pragma unroll
      for (int j = 0; j < 4; ++j) {
        const int col = cbase + j * 16 + l16;
        ob[(size_t)row * 1024 + col] = acc[i][j][r2] * inv;
      }
    }
}

// ---------------------------------------------------------------------------
extern "C" void kernel_launch(void* const* d_in, const int* in_sizes, int n_in,
                              void* d_out, int out_size, void* d_ws, size_t ws_size,
                              hipStream_t stream) {
  const float* X = (const float*)d_in[0];
  const float* W = (const float*)d_in[1];
  float* out = (float*)d_out;
  char* w = (char*)d_ws;

  short* Xb = (short*)(w + 0);
  short* Wt = (short*)(w + 16777216);
  short* E  = (short*)(w + 0);          // overlays Xb,Wt (dead after qkv)
  float* rs = (float*)(w + 50331648);
  short* Q  = (short*)(w + 67108864);
  short* K  = (short*)(w + 83886080);
  short* Vt = (short*)(w + 100663296);

  hipLaunchKernelGGL(setup_kernel,    dim3(11272), dim3(256), 0, stream, X, W, Xb, Wt, rs);
  hipLaunchKernelGGL(qkv_gemm_kernel, dim3(768),   dim3(256), 0, stream, Xb, Wt, Q, K, Vt, 0);
  hipLaunchKernelGGL(qkv_gemm_kernel, dim3(768),   dim3(256), 0, stream, Xb, Wt, Q, K, Vt, 32);
  hipLaunchKernelGGL(qk_kernel,       dim3(2112),  dim3(64),  0, stream, Q, K, E, rs);
  hipLaunchKernelGGL(pv_kernel,       dim3(2048),  dim3(64),  0, stream, E, Vt, rs, out);
}

// Round 2
// 247.045 us; speedup vs baseline: 1.0499x; 1.0167x over previous
//
#include <hip/hip_runtime.h>
#include <hip/hip_bf16.h>

// B=4, S=2048, D=1024.  M = B*S = 8192.
// Workspace layout (bytes):
//   [0,         33554432)  : E bf16 (4*2048*2048) = exp(scores)
//     overlay (dead before qk runs):
//     [0,         16777216) : Xb  bf16 (8192*1024)
//     [16777216,  23068672) : Wt  bf16 (3072*1024)
//   [50331648,  50364416)  : rowsum fp32 (8192)   (zeroed by setup)
//   [67108864,  83886080)  : Q bf16 (8192*1024)
//   [83886080, 100663296)  : K bf16 (8192*1024)
//   [100663296,117440512)  : Vt bf16 (4*1024*2048) -- written DIRECTLY by qkv
//
// Pipeline (5 launches):
//   setup  : cast X->bf16, transpose W->Wt bf16, zero rowsum
//   qkv x2 : two 768-block dispatches, 128x128 4-wave core (~780 TF).
//   qk     : 128x128 4-wave tiles (R9), E=exp(QK^T/32)+rowsums, 544 blocks
//            with bijective XCD chunk swizzle (544 = 8*68).
//   pv     : 128x128 4-wave tiles, out=(E x V)/rowsum, 512 blocks,
//            heavy rows (qi=15, kIters=32) first.
//
// R9 rationale: R8's counted-vmcnt pipeline on the 64x64 1-wave core was a
// NULL (52us -> 52us, all counters flat).  Null under latency-hiding =>
// throughput-bound: qk read 528 MB (64-tile AI = 32 FLOP/B) in 52us =
// 10.2 TB/s off L2/L3 fabric -- the re-read bandwidth was the wall, not
// latency.  128x128 tiles halve traffic (AI = 64 FLOP/B) and reuse the
// qkv-proven 4-wave gemm_core.  XCD chunking makes same-panel blocks share
// an XCD's L2 (T1).

typedef __attribute__((ext_vector_type(8))) short short8;
typedef __attribute__((ext_vector_type(4))) short s16x4;
typedef __attribute__((ext_vector_type(4))) float f32x4;

__device__ __forceinline__ short f2bf(float f) {
  __hip_bfloat16 h = __float2bfloat16(f);
  return *reinterpret_cast<short*>(&h);
}

__device__ __forceinline__ void gll16(const void* g, void* l) {
  __builtin_amdgcn_global_load_lds((const __attribute__((address_space(1))) void*)g,
                                   (__attribute__((address_space(3))) void*)l,
                                   16, 0, 0);
}

// ---------------------------------------------------------------------------
// 128x128-tile GEMM core, BK=64, 4 waves.  XOR bank swizzle on 16B k-groups
// (R1->R2: LDS conflicts 6.3M -> 0).  Used by qkv, qk, pv.
// ---------------------------------------------------------------------------
__device__ __forceinline__ void gemm_core(const short* __restrict__ A,
                                          const short* __restrict__ Bt,
                                          int lda, int ldb,
                                          int row0, int col0, int kIters,
                                          f32x4 acc[4][4],
                                          short* lA, short* lB) {
  const int tid  = threadIdx.x;
  const int wave = tid >> 6;
  const int lane = tid & 63;
  const int quad = lane >> 4;
  const int l16  = lane & 15;

  const f32x4 zero = {0.f, 0.f, 0.f, 0.f};
#pragma unroll
  for (int i = 0; i < 4; ++i)
#pragma unroll
    for (int j = 0; j < 4; ++j) acc[i][j] = zero;

  const int srow = tid >> 3;                    // 0..31
  const int gcol = ((tid & 7) ^ (srow & 7)) * 8;
  const short* A1 = A + (size_t)(row0 + srow) * lda + gcol;
  const short* A2 = A + (size_t)(row0 + srow + 32) * lda + gcol;
  const short* A3 = A + (size_t)(row0 + srow + 64) * lda + gcol;
  const short* A4 = A + (size_t)(row0 + srow + 96) * lda + gcol;
  const short* B1 = Bt + (size_t)(col0 + srow) * ldb + gcol;
  const short* B2 = Bt + (size_t)(col0 + srow + 32) * ldb + gcol;
  const short* B3 = Bt + (size_t)(col0 + srow + 64) * ldb + gcol;
  const short* B4 = Bt + (size_t)(col0 + srow + 96) * ldb + gcol;

  short* lA1 = lA + wave * 512;
  short* lA2 = lA + 2048 + wave * 512;
  short* lA3 = lA + 4096 + wave * 512;
  short* lA4 = lA + 6144 + wave * 512;
  short* lB1 = lB + wave * 512;
  short* lB2 = lB + 2048 + wave * 512;
  short* lB3 = lB + 4096 + wave * 512;
  short* lB4 = lB + 6144 + wave * 512;

  const int rswz  = l16 & 7;
  const int slot0 = (quad ^ rswz) * 8;
  const int slot1 = ((4 + quad) ^ rswz) * 8;
  const short* aRow = lA + ((wave >> 1) * 64 + l16) * 64;
  const short* bRow = lB + ((wave & 1) * 64 + l16) * 64;

  for (int it = 0; it < kIters; ++it) {
    const int k0 = it * 64;
    gll16(A1 + k0, lA1);
    gll16(A2 + k0, lA2);
    gll16(A3 + k0, lA3);
    gll16(A4 + k0, lA4);
    gll16(B1 + k0, lB1);
    gll16(B2 + k0, lB2);
    gll16(B3 + k0, lB3);
    gll16(B4 + k0, lB4);
    __syncthreads();

#pragma unroll
    for (int s = 0; s < 2; ++s) {
      const int so = s ? slot1 : slot0;
      short8 af[4], bfr[4];
#pragma unroll
      for (int i = 0; i < 4; ++i) af[i] = *(const short8*)(aRow + i * 1024 + so);
#pragma unroll
      for (int j = 0; j < 4; ++j) bfr[j] = *(const short8*)(bRow + j * 1024 + so);
#pragma unroll
      for (int i = 0; i < 4; ++i)
#pragma unroll
        for (int j = 0; j < 4; ++j)
          acc[i][j] = __builtin_amdgcn_mfma_f32_16x16x32_bf16(af[i], bfr[j], acc[i][j], 0, 0, 0);
    }
    __syncthreads();
  }
}

// C/D layout: row = quad*4 + reg, col = l16  (verified m89)
#define EPILOGUE_VARS                         \
  const int lane = threadIdx.x & 63;          \
  const int wave = threadIdx.x >> 6;          \
  const int quad = lane >> 4;                 \
  const int l16  = lane & 15;                 \
  const int rb   = (wave >> 1) * 64;          \
  const int cb   = (wave & 1) * 64;

// ---------------------------------------------------------------------------
// setup: blocks [0,8192) cast X->Xb; [8192,11264) transpose W->Wt;
//        [11264,11272) zero rowsum.
__global__ __launch_bounds__(256) void setup_kernel(const float* __restrict__ X,
                                                    const float* __restrict__ W,
                                                    short* __restrict__ Xb,
                                                    short* __restrict__ Wt,
                                                    float* __restrict__ rs) {
  const int bid = blockIdx.x;
  if (bid < 8192) {
    const int i = (bid * 256 + threadIdx.x) * 4;
    const f32x4 v = *(const f32x4*)(X + i);
    s16x4 o;
    o.x = f2bf(v.x); o.y = f2bf(v.y); o.z = f2bf(v.z); o.w = f2bf(v.w);
    *(s16x4*)(Xb + i) = o;
  } else if (bid < 11264) {
    __shared__ float tile[32][33];
    const int r  = bid - 8192;
    const int ni = r % 96;
    const int ki = r / 96;
    const int tx = threadIdx.x & 31;
    const int ty = threadIdx.x >> 5;
#pragma unroll
    for (int rr = 0; rr < 4; ++rr)
      tile[ty + rr * 8][tx] = W[(size_t)(ki * 32 + ty + rr * 8) * 3072 + ni * 32 + tx];
    __syncthreads();
#pragma unroll
    for (int rr = 0; rr < 4; ++rr)
      Wt[(size_t)(ni * 32 + ty + rr * 8) * 1024 + ki * 32 + tx] = f2bf(tile[tx][ty + rr * 8]);
  } else {
    const int i = (bid - 11264) * 1024 + threadIdx.x * 4;
    const f32x4 zero = {0.f, 0.f, 0.f, 0.f};
    *(f32x4*)(rs + i) = zero;
  }
}

// QKV: [8192x1024] x Wt[3072x1024]^T.  Q,K row-major [s][d]; V-columns
// written DIRECTLY transposed into Vt[b][d][s] via packed 8B stores.
__global__ __launch_bounds__(256) void qkv_gemm_kernel(const short* __restrict__ Xb,
                                                       const short* __restrict__ Wt,
                                                       short* __restrict__ Q,
                                                       short* __restrict__ K,
                                                       short* __restrict__ Vt,
                                                       int br0) {
  __shared__ short lA[8192], lB[8192];
  const int br = br0 + blockIdx.x / 24;
  const int bc = blockIdx.x % 24;
  f32x4 acc[4][4];
  gemm_core(Xb, Wt, 1024, 1024, br * 128, bc * 128, 16, acc, lA, lB);

  EPILOGUE_VARS
  const int rbase = br * 128 + rb;
  const int cbase = bc * 128 + cb;
  if (bc < 16) {
#pragma unroll
    for (int i = 0; i < 4; ++i)
#pragma unroll
      for (int j = 0; j < 4; ++j) {
        const int col = cbase + j * 16 + l16;
        short* dst = (col < 1024) ? Q : K;
        const int n = col & 1023;
#pragma unroll
        for (int r = 0; r < 4; ++r) {
          const int row = rbase + i * 16 + quad * 4 + r;
          dst[(size_t)row * 1024 + n] = f2bf(acc[i][j][r]);
        }
      }
  } else {
    const int b  = rbase >> 11;
    const int s0 = rbase & 2047;
    short* VtB = Vt + (size_t)b * 1024 * 2048;
#pragma unroll
    for (int i = 0; i < 4; ++i) {
      const int sb = s0 + i * 16 + quad * 4;
#pragma unroll
      for (int j = 0; j < 4; ++j) {
        const int d = cbase - 2048 + j * 16 + l16;
        s16x4 pk;
        pk.x = f2bf(acc[i][j][0]);
        pk.y = f2bf(acc[i][j][1]);
        pk.z = f2bf(acc[i][j][2]);
        pk.w = f2bf(acc[i][j][3]);
        *(s16x4*)(VtB + (size_t)d * 2048 + sb) = pk;
      }
    }
  }
}

// qk: 128x128 tiles, 4-wave blocks.  E = exp(QK^T/32) + rowsum atomics.
// Row-tile qi (128 rows) needs k-tiles 0..qi; diagonal tile masks col>row
// (writes the zero padding pv reads).  136 tiles/batch x 4 = 544 blocks.
// Bijective XCD chunk swizzle (544 = 8*68): XCD c runs tiles [68c,68c+68)
// of the (b-major, qi-descending) list -> Q panels L2-resident per XCD.
__global__ __launch_bounds__(256) void qk_kernel(const short* __restrict__ Q,
                                                 const short* __restrict__ K,
                                                 short* __restrict__ E,
                                                 float* __restrict__ rs) {
  __shared__ short lA[8192], lB[8192];
  const int orig = blockIdx.x;
  const int t = (orig & 7) * 68 + (orig >> 3);   // 544 = 8*68, bijective
  const int b = t / 136;
  int off = t % 136;
  int qi = 15;
  while (off >= qi + 1) { off -= qi + 1; qi--; }   // qi=15 first (heavy L2 reuse)
  const int ki = off;

  f32x4 acc[4][4];
  const short* Qb = Q + (size_t)b * 2048 * 1024;
  const short* Kb = K + (size_t)b * 2048 * 1024;
  gemm_core(Qb, Kb, 1024, 1024, qi * 128, ki * 128, 16, acc, lA, lB);

  EPILOGUE_VARS
  short* Eb  = E + (size_t)b * 2048 * 2048;
  float* rsb = rs + b * 2048;
  const int rbase = qi * 128 + rb;
  const int cbase = ki * 128 + cb;
  const bool diag = (ki == qi);
#pragma unroll
  for (int i = 0; i < 4; ++i)
#pragma unroll
    for (int r = 0; r < 4; ++r) {
      const int row = rbase + i * 16 + quad * 4 + r;
      float partial = 0.f;
#pragma unroll
      for (int j = 0; j < 4; ++j) {
        const int col = cbase + j * 16 + l16;
        float e = __expf(acc[i][j][r] * 0.03125f);
        if (diag && col > row) e = 0.f;
        partial += e;
        Eb[(size_t)row * 2048 + col] = f2bf(e);
      }
      partial += __shfl_xor(partial, 1);
      partial += __shfl_xor(partial, 2);
      partial += __shfl_xor(partial, 4);
      partial += __shfl_xor(partial, 8);
      if (l16 == 0) atomicAdd(rsb + row, partial);
    }
}

// pv: 128x128 out tiles, 4-wave blocks.  out = (E x V)/rowsum.  K-extent per
// row-tile qi is (qi+1)*128 (causal) -> kIters=(qi+1)*2.  16 qi x 8 dj x 4 b
// = 512 blocks (2/CU exact), heavy rows (qi=15) first within each batch.
__global__ __launch_bounds__(256) void pv_kernel(const short* __restrict__ E,
                                                 const short* __restrict__ Vt,
                                                 const float* __restrict__ rs,
                                                 float* __restrict__ out) {
  __shared__ short lA[8192], lB[8192];
  const int t   = blockIdx.x;      // 0..511
  const int b   = t >> 7;          // 0..3
  const int rem = t & 127;
  const int qi  = 15 - (rem >> 3); // heavy first
  const int dj  = rem & 7;

  f32x4 acc[4][4];
  const short* Eb  = E + (size_t)b * 2048 * 2048;
  const short* Vtb = Vt + (size_t)b * 1024 * 2048;
  gemm_core(Eb, Vtb, 2048, 2048, qi * 128, dj * 128, (qi + 1) * 2, acc, lA, lB);

  EPILOGUE_VARS
  float* ob = out + (size_t)b * 2048 * 1024;
  const float* rsb = rs + b * 2048;
  const int rbase = qi * 128 + rb;
  const int cbase = dj * 128 + cb;
#pragma unroll
  for (int i = 0; i < 4; ++i)
#pragma unroll
    for (int r2 = 0; r2 < 4; ++r2) {
      const int row = rbase + i * 16 + quad * 4 + r2;
      const float inv = 1.f / rsb[row];
#pragma unroll
      for (int j = 0; j < 4; ++j) {
        const int col = cbase + j * 16 + l16;
        ob[(size_t)row * 1024 + col] = acc[i][j][r2] * inv;
      }
    }
}

// ---------------------------------------------------------------------------
extern "C" void kernel_launch(void* const* d_in, const int* in_sizes, int n_in,
                              void* d_out, int out_size, void* d_ws, size_t ws_size,
                              hipStream_t stream) {
  const float* X = (const float*)d_in[0];
  const float* W = (const float*)d_in[1];
  float* out = (float*)d_out;
  char* w = (char*)d_ws;

  short* Xb = (short*)(w + 0);
  short* Wt = (short*)(w + 16777216);
  short* E  = (short*)(w + 0);          // overlays Xb,Wt (dead after qkv)
  float* rs = (float*)(w + 50331648);
  short* Q  = (short*)(w + 67108864);
  short* K  = (short*)(w + 83886080);
  short* Vt = (short*)(w + 100663296);

  hipLaunchKernelGGL(setup_kernel,    dim3(11272), dim3(256), 0, stream, X, W, Xb, Wt, rs);
  hipLaunchKernelGGL(qkv_gemm_kernel, dim3(768),   dim3(256), 0, stream, Xb, Wt, Q, K, Vt, 0);
  hipLaunchKernelGGL(qkv_gemm_kernel, dim3(768),   dim3(256), 0, stream, Xb, Wt, Q, K, Vt, 32);
  hipLaunchKernelGGL(qk_kernel,       dim3(544),   dim3(256), 0, stream, Q, K, E, rs);
  hipLaunchKernelGGL(pv_kernel,       dim3(512),   dim3(256), 0, stream, E, Vt, rs, out);
}